// Round 6
// baseline (754.286 us; speedup 1.0000x reference)
//
#include <hip/hip_runtime.h>
#include <hip/hip_bf16.h>
#include <math.h>
#include <stdint.h>

#define NTRY  50
#define BROWS 131072
// output section offsets (floats): out[B*7] | mu[B*32] | kappa[B]
#define OFF_OUT_MU    917504
#define OFF_OUT_KAPPA 5111808

__device__ __forceinline__ uint32_t rotl32(uint32_t x, int r){ return (x << r) | (x >> (32 - r)); }

// Exact JAX threefry2x32 (20 rounds, 5 key injections) — matches jax/_src/prng.py
__device__ __forceinline__ void threefry2x32(uint32_t k0, uint32_t k1,
                                             uint32_t c0, uint32_t c1,
                                             uint32_t& o0, uint32_t& o1){
  const uint32_t k2 = k0 ^ k1 ^ 0x1BD11BDAu;
  uint32_t x0 = c0 + k0;
  uint32_t x1 = c1 + k1;
#define TF_R(r) { x0 += x1; x1 = rotl32(x1, (r)); x1 ^= x0; }
  TF_R(13) TF_R(15) TF_R(26) TF_R(6)
  x0 += k1; x1 += k2 + 1u;
  TF_R(17) TF_R(29) TF_R(16) TF_R(24)
  x0 += k2; x1 += k0 + 2u;
  TF_R(13) TF_R(15) TF_R(26) TF_R(6)
  x0 += k0; x1 += k1 + 3u;
  TF_R(17) TF_R(29) TF_R(16) TF_R(24)
  x0 += k1; x1 += k2 + 4u;
  TF_R(13) TF_R(15) TF_R(26) TF_R(6)
  x0 += k2; x1 += k0 + 5u;
#undef TF_R
  o0 = x0; o1 = x1;
}

// Partitionable random_bits for bit_width=32: bits = out0 ^ out1, counter=(0, idx)
__device__ __forceinline__ uint32_t tf_bits32(uint32_t k0, uint32_t k1, uint32_t idx){
  uint32_t a, b;
  threefry2x32(k0, k1, 0u, idx, a, b);
  return a ^ b;
}

// JAX uniform bit->float: (bits>>9)|0x3f800000 as float, minus 1  -> [0,1)
__device__ __forceinline__ float bits_to_unit(uint32_t bits){
  return __uint_as_float((bits >> 9) | 0x3f800000u) - 1.0f;
}

// f32 log computed via f64 (≈ correctly rounded f32 log)
__device__ __forceinline__ float alogf(float x){
  return (float)log((double)x);
}

// XLA f32 ErfInv polynomial (Giles) — same as xla math.cc ErfInv32
__device__ __forceinline__ float erfinv_f(float x){
  float w = -log1pf(-x * x);
  float p;
  if (w < 5.0f){
    w -= 2.5f;
    p = 2.81022636e-08f;
    p = fmaf(p, w, 3.43273939e-07f);
    p = fmaf(p, w, -3.5233877e-06f);
    p = fmaf(p, w, -4.39150654e-06f);
    p = fmaf(p, w, 0.00021858087f);
    p = fmaf(p, w, -0.00125372503f);
    p = fmaf(p, w, -0.00417768164f);
    p = fmaf(p, w, 0.246640727f);
    p = fmaf(p, w, 1.50140941f);
  } else {
    w = sqrtf(w) - 3.0f;
    p = -0.000200214257f;
    p = fmaf(p, w, 0.000100950558f);
    p = fmaf(p, w, 0.00134934322f);
    p = fmaf(p, w, -0.00367342844f);
    p = fmaf(p, w, 0.00573950773f);
    p = fmaf(p, w, -0.0076224613f);
    p = fmaf(p, w, 0.00943887047f);
    p = fmaf(p, w, 1.00167406f);
    p = fmaf(p, w, 2.83297682f);
  }
  return p * x;
}

// ws layout: keys u32[0..200) = 50 * {k1.x,k1.y,k2.x,k2.y}; u32[200..202) = kv
//            float W2T[512][32] at byte offset 1024
__global__ void prep_kernel(const float* __restrict__ W2, const int* __restrict__ seedp,
                            uint32_t* __restrict__ keys, float* __restrict__ W2T)
{
  const int t = threadIdx.x;
  const uint32_t seed = (uint32_t)seedp[0];
  if (t < NTRY){
    uint32_t f0, f1, a0, a1, b0, b1;
    threefry2x32(0u, seed, 0u, (uint32_t)t, f0, f1);
    threefry2x32(f0, f1, 0u, 0u, a0, a1);
    threefry2x32(f0, f1, 0u, 1u, b0, b1);
    keys[t*4+0] = a0;  // k1
    keys[t*4+1] = a1;
    keys[t*4+2] = b0;  // k2
    keys[t*4+3] = b1;
  } else if (t == NTRY){
    uint32_t f0, f1;
    threefry2x32(0u, seed, 0u, 10000u, f0, f1);
    keys[200] = f0; keys[201] = f1;
  }
  // transpose W2 [32,512] -> W2T [512,32]
  for (int i = t; i < 16384; i += 256){
    int o2 = i >> 9, o1 = i & 511;
    W2T[o1*32 + o2] = W2[i];
  }
}

// Fused kernel: block=512, grid=256 (1 block/CU, 8 waves/CU = 2 waves/SIMD).
// Weight delivery split across BOTH uniform-data pipes in BOTH matmul phases
// (the per-CU LDS pipe writes back 1 KiB/wave-instr even for broadcasts —
//  ~4-12 cyc each — so all-LDS over-subscribes it; all-scalar chains K$-miss
//  latency under SGPR pressure; half-and-half runs the pipes concurrently):
//  - phase A: Wmu rows 0..15 via LDS broadcast; rows 16..31 + Wk via
//    s_load→SGPR→VALU-operand (pointer select is compile-time per unrolled o).
//  - phase C: W1 via s_load ∥ W2T via LDS broadcast.
// h loads double-buffered in registers (TLP is structurally 2 waves/SIMD, so
// ILP must hide HBM latency). LDS 64 KiB, one buffer reused: Wmu[0:16) for
// phase A, restaged to W2T for phase C under phase B.
__global__ __launch_bounds__(512, 2) void fused_kernel(
    const float* __restrict__ h,
    const float* __restrict__ Wmu, const float* __restrict__ bmu,
    const float* __restrict__ Wk,  const float* __restrict__ bk,
    const float* __restrict__ W1,  const float* __restrict__ b1,
    const float* __restrict__ b2,
    const float* __restrict__ W3,  const float* __restrict__ b3,
    const float* __restrict__ W2T,
    const uint32_t* __restrict__ keys,
    float* __restrict__ out)
{
  __shared__ __align__(16) float lds[16384];   // 64 KiB
  const int tid = threadIdx.x;
  const int b = blockIdx.x * 512 + tid;

  const float4* h4 = reinterpret_cast<const float4*>(h + (size_t)b * 512);

  // prefetch h chunk 0 BEFORE the LDS stage: overlaps stage + barrier latency
  float4 hbuf[8];
  #pragma unroll
  for (int q = 0; q < 8; ++q) hbuf[q] = h4[q];

  // ---------------- stage Wmu rows 0..15 (16x512 = 32 KiB) into LDS ---------
  {
    const float4* Wmu4 = reinterpret_cast<const float4*>(Wmu);
    float4* lds4 = reinterpret_cast<float4*>(lds);
    #pragma unroll
    for (int q = 0; q < 4; ++q){                 // 2048 float4 / 512 threads
      lds4[tid + q*512] = Wmu4[tid + q*512];
    }
  }
  __syncthreads();

  // ---------------- phase A: 33 dots of length 512 (mu rows + kappa) --------
  // identical accumulation order to the verified kernel (c = 0..511 in order);
  // per-o delivery mechanism differs but each dot's FMA chain is unchanged.
  float acc[33];
  #pragma unroll
  for (int o = 0; o < 33; ++o) acc[o] = 0.0f;
  #pragma unroll 1
  for (int ch = 0; ch < 16; ++ch){
    // unpack current chunk, then immediately issue next chunk's loads so the
    // 8 global_load_dwordx4 are in flight under this chunk's 1056 FMAs
    float hv[32];
    #pragma unroll
    for (int q = 0; q < 8; ++q){
      float4 f = hbuf[q];
      hv[q*4+0] = f.x; hv[q*4+1] = f.y; hv[q*4+2] = f.z; hv[q*4+3] = f.w;
    }
    if (ch < 15){
      #pragma unroll
      for (int q = 0; q < 8; ++q) hbuf[q] = h4[(ch+1)*8 + q];
    }
    #pragma unroll
    for (int o = 0; o < 33; ++o){
      float a = acc[o];
      if (o < 16){
        // LDS broadcast path
        const float4* wr4 = reinterpret_cast<const float4*>(&lds[o*512 + ch*32]);
        #pragma unroll
        for (int q = 0; q < 8; ++q){
          float4 wq = wr4[q];
          a += hv[q*4+0] * wq.x;
          a += hv[q*4+1] * wq.y;
          a += hv[q*4+2] * wq.z;
          a += hv[q*4+3] * wq.w;
        }
      } else {
        // scalar path: o is a compile-time constant here -> SGPR base + imm
        const float* wr = (o < 32) ? (Wmu + o*512 + ch*32) : (Wk + ch*32);
        #pragma unroll
        for (int c = 0; c < 32; ++c) a += hv[c] * wr[c];
      }
      acc[o] = a;
    }
  }

  float mu[32]; float nsq = 0.0f;
  #pragma unroll
  for (int o = 0; o < 32; ++o){ float m = acc[o] + bmu[o]; mu[o] = m; nsq += m*m; }
  const float invn = 1.0f / fmaxf(sqrtf(nsq), 1e-12f);
  #pragma unroll
  for (int o = 0; o < 32; ++o) mu[o] *= invn;

  const float xk = acc[32] + bk[0];
  const float kappa = (float)log1p(exp((double)xk)) + 1.0f;   // softplus(x)+1

  // write mu and kappa outputs
  {
    float4* mo = reinterpret_cast<float4*>(out + OFF_OUT_MU + (size_t)b * 32);
    #pragma unroll
    for (int q = 0; q < 8; ++q){
      float4 f; f.x = mu[q*4+0]; f.y = mu[q*4+1]; f.z = mu[q*4+2]; f.w = mu[q*4+3];
      mo[q] = f;
    }
    out[OFF_OUT_KAPPA + b] = kappa;
  }

  // ---------------- restage LDS: W2T (64 KiB), hidden under phase B ---------
  __syncthreads();                               // everyone done reading Wmu region
  {
    const float4* W2T_4 = reinterpret_cast<const float4*>(W2T);
    float4 tmp[8];
    #pragma unroll
    for (int q = 0; q < 8; ++q){                 // batched: 8 loads in flight, one latency
      tmp[q] = W2T_4[tid + q*512];
    }
    float4* lds4 = reinterpret_cast<float4*>(lds);
    #pragma unroll
    for (int q = 0; q < 8; ++q){
      lds4[tid + q*512] = tmp[q];
    }
  }

  // ---------------- phase B: Wood's rejection sampling ----------------------
  const uint32_t ub = (uint32_t)b;

  float w = 0.0f; bool done = false;
  #pragma unroll 2
  for (int i = 0; i < NTRY; ++i){
    #pragma clang fp contract(off)
    const uint32_t K0 = keys[i*4+0], K1 = keys[i*4+1];
    const uint32_t K2 = keys[i*4+2], K3 = keys[i*4+3];
    const float u1 = bits_to_unit(tf_bits32(K0, K1, ub));   // w_cand
    const float u2 = bits_to_unit(tf_bits32(K2, K3, ub));   // log_r
    const float wc   = 2.0f * u1 - 1.0f;
    const float ww   = wc * wc;
    const float omw2 = fmaxf(1.0f - ww, 1e-38f);
    const float lg   = alogf(omw2);
    const float lp   = kappa * wc + 14.5f * lg;   // 0.5*(alpha-2)=14.5
    const float lr   = alogf(u2 + 1e-38f);
    const bool  cnd  = (lr + kappa <= lp) && !done;
    if (cnd){ w = wc; done = true; }
  }
  w = fminf(fmaxf(w, -1.0f), 1.0f);

  // normals on S^{d-2}: element e = b*31+j, counter (0, e), bits = x0^x1
  const uint32_t kv0 = keys[200], kv1 = keys[201];
  float v[31]; float vns = 0.0f;
  const uint32_t e0 = ub * 31u;
  #pragma unroll
  for (int j = 0; j < 31; ++j){
    const float uf01 = bits_to_unit(tf_bits32(kv0, kv1, e0 + (uint32_t)j));
    const float u = fmaxf(uf01 * 2.0f + (-0.99999994f), -0.99999994f); // uniform in (lo,1)
    const float g = 1.4142135623730951f * erfinv_f(u);
    v[j] = g; vns += g * g;
  }
  const float invvn = 1.0f / fmaxf(sqrtf(vns), 1e-12f);
  const float st = sqrtf(fmaxf(1.0f - w * w, 1e-38f));

  float zt[32];
  #pragma unroll
  for (int j = 0; j < 31; ++j) zt[j] = st * (v[j] * invvn);
  zt[31] = w;

  // Householder reflection: u = l2norm(e_d - mu); z = zt - 2 (zt.u) u
  float ue[32]; float uns = 0.0f;
  #pragma unroll
  for (int o = 0; o < 32; ++o){
    float e = ((o == 31) ? 1.0f : 0.0f) - mu[o];
    ue[o] = e; uns += e * e;
  }
  const float invun = 1.0f / fmaxf(sqrtf(uns), 1e-12f);
  float dot = 0.0f;
  #pragma unroll
  for (int o = 0; o < 32; ++o){ ue[o] *= invun; dot += zt[o] * ue[o]; }
  float z[32];
  #pragma unroll
  for (int o = 0; o < 32; ++o) z[o] = zt[o] - 2.0f * dot * ue[o];

  // ---------------- phase C: MLP 32 -> 512 -> 32 -> 7 -----------------------
  __syncthreads();                               // W2T staged (long before: phase B >> stage)
  float x2a[32];
  #pragma unroll
  for (int o2 = 0; o2 < 32; ++o2) x2a[o2] = b2[o2];
  #pragma unroll 2
  for (int o1 = 0; o1 < 512; ++o1){
    const float* w1r = W1 + o1*32;     // uniform -> s_load -> VALU SGPR-operand broadcast
    float t = b1[o1];
    #pragma unroll
    for (int j = 0; j < 32; ++j) t += z[j] * w1r[j];
    t = fmaxf(t, 0.0f);
    const float4* w2r4 = reinterpret_cast<const float4*>(&lds[o1*32]);  // uniform -> LDS broadcast
    #pragma unroll
    for (int q = 0; q < 8; ++q){
      float4 w2q = w2r4[q];
      x2a[q*4+0] += t * w2q.x;
      x2a[q*4+1] += t * w2q.y;
      x2a[q*4+2] += t * w2q.z;
      x2a[q*4+3] += t * w2q.w;
    }
  }
  #pragma unroll
  for (int o2 = 0; o2 < 32; ++o2) x2a[o2] = fmaxf(x2a[o2], 0.0f);

  float* orow = out + (size_t)b * 7;
  #pragma unroll
  for (int k = 0; k < 7; ++k){
    const float* w3r = W3 + k*32;      // tiny, one-shot: leave as uniform s_load
    float s = b3[k];
    #pragma unroll
    for (int o2 = 0; o2 < 32; ++o2) s += x2a[o2] * w3r[o2];
    orow[k] = s;
  }
}

extern "C" void kernel_launch(void* const* d_in, const int* in_sizes, int n_in,
                              void* d_out, int out_size, void* d_ws, size_t ws_size,
                              hipStream_t stream)
{
  const float* h   = (const float*)d_in[0];
  const float* Wmu = (const float*)d_in[1];
  const float* bmu = (const float*)d_in[2];
  const float* Wk  = (const float*)d_in[3];
  const float* bk  = (const float*)d_in[4];
  const float* W1  = (const float*)d_in[5];
  const float* b1  = (const float*)d_in[6];
  const float* W2  = (const float*)d_in[7];
  const float* b2  = (const float*)d_in[8];
  const float* W3  = (const float*)d_in[9];
  const float* b3  = (const float*)d_in[10];
  const int* seed  = (const int*)d_in[11];

  uint32_t* keys = (uint32_t*)d_ws;
  float* W2T = (float*)((char*)d_ws + 1024);
  float* out = (float*)d_out;

  hipLaunchKernelGGL(prep_kernel, dim3(1), dim3(256), 0, stream, W2, seed, keys, W2T);
  hipLaunchKernelGGL(fused_kernel, dim3(BROWS/512), dim3(512), 0, stream,
                     h, Wmu, bmu, Wk, bk, W1, b1, b2, W3, b3, W2T, keys, out);
}

// Round 8
// 747.474 us; speedup vs baseline: 1.0091x; 1.0091x over previous
//
#include <hip/hip_runtime.h>
#include <hip/hip_bf16.h>
#include <math.h>
#include <stdint.h>

#define NTRY  50
#define BROWS 131072
// output section offsets (floats): out[B*7] | mu[B*32] | kappa[B]
#define OFF_OUT_MU    917504
#define OFF_OUT_KAPPA 5111808

__device__ __forceinline__ uint32_t rotl32(uint32_t x, int r){ return (x << r) | (x >> (32 - r)); }

// Exact JAX threefry2x32 (20 rounds, 5 key injections) — matches jax/_src/prng.py
__device__ __forceinline__ void threefry2x32(uint32_t k0, uint32_t k1,
                                             uint32_t c0, uint32_t c1,
                                             uint32_t& o0, uint32_t& o1){
  const uint32_t k2 = k0 ^ k1 ^ 0x1BD11BDAu;
  uint32_t x0 = c0 + k0;
  uint32_t x1 = c1 + k1;
#define TF_R(r) { x0 += x1; x1 = rotl32(x1, (r)); x1 ^= x0; }
  TF_R(13) TF_R(15) TF_R(26) TF_R(6)
  x0 += k1; x1 += k2 + 1u;
  TF_R(17) TF_R(29) TF_R(16) TF_R(24)
  x0 += k2; x1 += k0 + 2u;
  TF_R(13) TF_R(15) TF_R(26) TF_R(6)
  x0 += k0; x1 += k1 + 3u;
  TF_R(17) TF_R(29) TF_R(16) TF_R(24)
  x0 += k1; x1 += k2 + 4u;
  TF_R(13) TF_R(15) TF_R(26) TF_R(6)
  x0 += k2; x1 += k0 + 5u;
#undef TF_R
  o0 = x0; o1 = x1;
}

// Partitionable random_bits for bit_width=32: bits = out0 ^ out1, counter=(0, idx)
__device__ __forceinline__ uint32_t tf_bits32(uint32_t k0, uint32_t k1, uint32_t idx){
  uint32_t a, b;
  threefry2x32(k0, k1, 0u, idx, a, b);
  return a ^ b;
}

// JAX uniform bit->float: (bits>>9)|0x3f800000 as float, minus 1  -> [0,1)
__device__ __forceinline__ float bits_to_unit(uint32_t bits){
  return __uint_as_float((bits >> 9) | 0x3f800000u) - 1.0f;
}

// f32 log computed via f64 (≈ correctly rounded f32 log)
__device__ __forceinline__ float alogf(float x){
  return (float)log((double)x);
}

// XLA f32 ErfInv polynomial (Giles) — same as xla math.cc ErfInv32
__device__ __forceinline__ float erfinv_f(float x){
  float w = -log1pf(-x * x);
  float p;
  if (w < 5.0f){
    w -= 2.5f;
    p = 2.81022636e-08f;
    p = fmaf(p, w, 3.43273939e-07f);
    p = fmaf(p, w, -3.5233877e-06f);
    p = fmaf(p, w, -4.39150654e-06f);
    p = fmaf(p, w, 0.00021858087f);
    p = fmaf(p, w, -0.00125372503f);
    p = fmaf(p, w, -0.00417768164f);
    p = fmaf(p, w, 0.246640727f);
    p = fmaf(p, w, 1.50140941f);
  } else {
    w = sqrtf(w) - 3.0f;
    p = -0.000200214257f;
    p = fmaf(p, w, 0.000100950558f);
    p = fmaf(p, w, 0.00134934322f);
    p = fmaf(p, w, -0.00367342844f);
    p = fmaf(p, w, 0.00573950773f);
    p = fmaf(p, w, -0.0076224613f);
    p = fmaf(p, w, 0.00943887047f);
    p = fmaf(p, w, 1.00167406f);
    p = fmaf(p, w, 2.83297682f);
  }
  return p * x;
}

// ws layout: keys u32[0..200) = 50 * {k1.x,k1.y,k2.x,k2.y}; u32[200..202) = kv
//            float W2T[512][32] at byte offset 1024
// Parallel prep: 64 blocks x 256 threads. Block 0 computes keys; all blocks
// transpose a write-coalesced slice (the old 1-block version serialized the
// whole GPU for ~200 us with stride-128B stores).
__global__ void prep_kernel(const float* __restrict__ W2, const int* __restrict__ seedp,
                            uint32_t* __restrict__ keys, float* __restrict__ W2T)
{
  const int t = threadIdx.x;
  if (blockIdx.x == 0){
    const uint32_t seed = (uint32_t)seedp[0];
    if (t < NTRY){
      uint32_t f0, f1, a0, a1, b0, b1;
      threefry2x32(0u, seed, 0u, (uint32_t)t, f0, f1);
      threefry2x32(f0, f1, 0u, 0u, a0, a1);
      threefry2x32(f0, f1, 0u, 1u, b0, b1);
      keys[t*4+0] = a0;  // k1
      keys[t*4+1] = a1;
      keys[t*4+2] = b0;  // k2
      keys[t*4+3] = b1;
    } else if (t == NTRY){
      uint32_t f0, f1;
      threefry2x32(0u, seed, 0u, 10000u, f0, f1);
      keys[200] = f0; keys[201] = f1;
    }
  }
  // transpose W2 [32,512] -> W2T [512,32]; j is the OUTPUT index -> coalesced
  // stores; strided reads hit L2 after first touch (64 KB total).
  const int j = blockIdx.x * 256 + t;           // 64*256 = 16384
  const int o1 = j >> 5, o2 = j & 31;
  W2T[j] = W2[o2*512 + o1];
}

// Fused kernel: block=512, grid=256 (1 block/CU, 8 waves/CU = 2 waves/SIMD).
// Weight delivery split across BOTH uniform-data pipes in BOTH matmul phases
// (the per-CU LDS pipe writes back 1 KiB/wave-instr even for broadcasts —
//  ~6-12 cyc each — so all-LDS over-subscribes it; all-scalar chains K$-miss
//  latency; half-and-half runs the pipes concurrently):
//  - phase A: Wmu rows 0..15 via LDS broadcast; rows 16..31 + Wk via
//    s_load→SGPR→VALU-operand (pointer select is compile-time per unrolled o).
//  - phase C: W1 via s_load; W2T rows 0..255 via LDS broadcast, rows 256..511
//    via s_load (two sequential o1 loops -> accumulation order unchanged).
// h loads double-buffered in registers (TLP is structurally 2 waves/SIMD, so
// ILP must hide HBM latency). LDS 32 KiB, one buffer reused: Wmu[0:16) for
// phase A, restaged to W2T[0:256) for phase C under phase B.
__global__ __launch_bounds__(512, 2) void fused_kernel(
    const float* __restrict__ h,
    const float* __restrict__ Wmu, const float* __restrict__ bmu,
    const float* __restrict__ Wk,  const float* __restrict__ bk,
    const float* __restrict__ W1,  const float* __restrict__ b1,
    const float* __restrict__ b2,
    const float* __restrict__ W3,  const float* __restrict__ b3,
    const float* __restrict__ W2T,
    const uint32_t* __restrict__ keys,
    float* __restrict__ out)
{
  __shared__ __align__(16) float lds[8192];    // 32 KiB
  const int tid = threadIdx.x;
  const int b = blockIdx.x * 512 + tid;

  const float4* h4 = reinterpret_cast<const float4*>(h + (size_t)b * 512);

  // prefetch h chunk 0 BEFORE the LDS stage: overlaps stage + barrier latency
  float4 hbuf[8];
  #pragma unroll
  for (int q = 0; q < 8; ++q) hbuf[q] = h4[q];

  // ---------------- stage Wmu rows 0..15 (16x512 = 32 KiB) into LDS ---------
  {
    const float4* Wmu4 = reinterpret_cast<const float4*>(Wmu);
    float4* lds4 = reinterpret_cast<float4*>(lds);
    #pragma unroll
    for (int q = 0; q < 4; ++q){                 // 2048 float4 / 512 threads
      lds4[tid + q*512] = Wmu4[tid + q*512];
    }
  }
  __syncthreads();

  // ---------------- phase A: 33 dots of length 512 (mu rows + kappa) --------
  // identical accumulation order to the verified kernel (c = 0..511 in order);
  // per-o delivery mechanism differs but each dot's FMA chain is unchanged.
  float acc[33];
  #pragma unroll
  for (int o = 0; o < 33; ++o) acc[o] = 0.0f;
  #pragma unroll 1
  for (int ch = 0; ch < 16; ++ch){
    // unpack current chunk, then immediately issue next chunk's loads so the
    // 8 global_load_dwordx4 are in flight under this chunk's 1056 FMAs
    float hv[32];
    #pragma unroll
    for (int q = 0; q < 8; ++q){
      float4 f = hbuf[q];
      hv[q*4+0] = f.x; hv[q*4+1] = f.y; hv[q*4+2] = f.z; hv[q*4+3] = f.w;
    }
    if (ch < 15){
      #pragma unroll
      for (int q = 0; q < 8; ++q) hbuf[q] = h4[(ch+1)*8 + q];
    }
    #pragma unroll
    for (int o = 0; o < 33; ++o){
      float a = acc[o];
      if (o < 16){
        // LDS broadcast path
        const float4* wr4 = reinterpret_cast<const float4*>(&lds[o*512 + ch*32]);
        #pragma unroll
        for (int q = 0; q < 8; ++q){
          float4 wq = wr4[q];
          a += hv[q*4+0] * wq.x;
          a += hv[q*4+1] * wq.y;
          a += hv[q*4+2] * wq.z;
          a += hv[q*4+3] * wq.w;
        }
      } else {
        // scalar path: o is a compile-time constant here -> SGPR base + imm
        const float* wr = (o < 32) ? (Wmu + o*512 + ch*32) : (Wk + ch*32);
        #pragma unroll
        for (int c = 0; c < 32; ++c) a += hv[c] * wr[c];
      }
      acc[o] = a;
    }
  }

  float mu[32]; float nsq = 0.0f;
  #pragma unroll
  for (int o = 0; o < 32; ++o){ float m = acc[o] + bmu[o]; mu[o] = m; nsq += m*m; }
  const float invn = 1.0f / fmaxf(sqrtf(nsq), 1e-12f);
  #pragma unroll
  for (int o = 0; o < 32; ++o) mu[o] *= invn;

  const float xk = acc[32] + bk[0];
  const float kappa = (float)log1p(exp((double)xk)) + 1.0f;   // softplus(x)+1

  // write mu and kappa outputs
  {
    float4* mo = reinterpret_cast<float4*>(out + OFF_OUT_MU + (size_t)b * 32);
    #pragma unroll
    for (int q = 0; q < 8; ++q){
      float4 f; f.x = mu[q*4+0]; f.y = mu[q*4+1]; f.z = mu[q*4+2]; f.w = mu[q*4+3];
      mo[q] = f;
    }
    out[OFF_OUT_KAPPA + b] = kappa;
  }

  // ---------------- restage LDS: W2T rows 0..255 (32 KiB), under phase B ----
  __syncthreads();                               // everyone done reading Wmu region
  {
    const float4* W2T_4 = reinterpret_cast<const float4*>(W2T);
    float4 tmp[4];
    #pragma unroll
    for (int q = 0; q < 4; ++q){                 // batched: 4 loads in flight, one latency
      tmp[q] = W2T_4[tid + q*512];
    }
    float4* lds4 = reinterpret_cast<float4*>(lds);
    #pragma unroll
    for (int q = 0; q < 4; ++q){
      lds4[tid + q*512] = tmp[q];
    }
  }

  // ---------------- phase B: Wood's rejection sampling ----------------------
  const uint32_t ub = (uint32_t)b;

  float w = 0.0f; bool done = false;
  #pragma unroll 2
  for (int i = 0; i < NTRY; ++i){
    #pragma clang fp contract(off)
    const uint32_t K0 = keys[i*4+0], K1 = keys[i*4+1];
    const uint32_t K2 = keys[i*4+2], K3 = keys[i*4+3];
    const float u1 = bits_to_unit(tf_bits32(K0, K1, ub));   // w_cand
    const float u2 = bits_to_unit(tf_bits32(K2, K3, ub));   // log_r
    const float wc   = 2.0f * u1 - 1.0f;
    const float ww   = wc * wc;
    const float omw2 = fmaxf(1.0f - ww, 1e-38f);
    const float lg   = alogf(omw2);
    const float lp   = kappa * wc + 14.5f * lg;   // 0.5*(alpha-2)=14.5
    const float lr   = alogf(u2 + 1e-38f);
    const bool  cnd  = (lr + kappa <= lp) && !done;
    if (cnd){ w = wc; done = true; }
    if (__all(done)) break;                       // exact: skipped iters can't change state
  }
  w = fminf(fmaxf(w, -1.0f), 1.0f);

  // normals on S^{d-2}: element e = b*31+j, counter (0, e), bits = x0^x1
  const uint32_t kv0 = keys[200], kv1 = keys[201];
  float v[31]; float vns = 0.0f;
  const uint32_t e0 = ub * 31u;
  #pragma unroll
  for (int j = 0; j < 31; ++j){
    const float uf01 = bits_to_unit(tf_bits32(kv0, kv1, e0 + (uint32_t)j));
    const float u = fmaxf(uf01 * 2.0f + (-0.99999994f), -0.99999994f); // uniform in (lo,1)
    const float g = 1.4142135623730951f * erfinv_f(u);
    v[j] = g; vns += g * g;
  }
  const float invvn = 1.0f / fmaxf(sqrtf(vns), 1e-12f);
  const float st = sqrtf(fmaxf(1.0f - w * w, 1e-38f));

  float zt[32];
  #pragma unroll
  for (int j = 0; j < 31; ++j) zt[j] = st * (v[j] * invvn);
  zt[31] = w;

  // Householder reflection: u = l2norm(e_d - mu); z = zt - 2 (zt.u) u
  float ue[32]; float uns = 0.0f;
  #pragma unroll
  for (int o = 0; o < 32; ++o){
    float e = ((o == 31) ? 1.0f : 0.0f) - mu[o];
    ue[o] = e; uns += e * e;
  }
  const float invun = 1.0f / fmaxf(sqrtf(uns), 1e-12f);
  float dot = 0.0f;
  #pragma unroll
  for (int o = 0; o < 32; ++o){ ue[o] *= invun; dot += zt[o] * ue[o]; }
  float z[32];
  #pragma unroll
  for (int o = 0; o < 32; ++o) z[o] = zt[o] - 2.0f * dot * ue[o];

  // ---------------- phase C: MLP 32 -> 512 -> 32 -> 7 -----------------------
  __syncthreads();                               // W2T staged (long before: phase B >> stage)
  float x2a[32];
  #pragma unroll
  for (int o2 = 0; o2 < 32; ++o2) x2a[o2] = b2[o2];
  // rows 0..255: W1 scalar || W2T via LDS broadcast
  #pragma unroll 2
  for (int o1 = 0; o1 < 256; ++o1){
    const float* w1r = W1 + o1*32;     // uniform -> s_load -> VALU SGPR-operand broadcast
    float t = b1[o1];
    #pragma unroll
    for (int j = 0; j < 32; ++j) t += z[j] * w1r[j];
    t = fmaxf(t, 0.0f);
    const float4* w2r4 = reinterpret_cast<const float4*>(&lds[o1*32]);  // uniform -> LDS broadcast
    #pragma unroll
    for (int q = 0; q < 8; ++q){
      float4 w2q = w2r4[q];
      x2a[q*4+0] += t * w2q.x;
      x2a[q*4+1] += t * w2q.y;
      x2a[q*4+2] += t * w2q.z;
      x2a[q*4+3] += t * w2q.w;
    }
  }
  // rows 256..511: W1 scalar || W2T scalar (halves per-CU LDS-pipe pressure;
  // o1 order preserved -> bit-identical accumulation)
  #pragma unroll 2
  for (int o1 = 256; o1 < 512; ++o1){
    const float* w1r = W1 + o1*32;
    float t = b1[o1];
    #pragma unroll
    for (int j = 0; j < 32; ++j) t += z[j] * w1r[j];
    t = fmaxf(t, 0.0f);
    const float* w2r = W2T + o1*32;    // uniform -> s_load
    #pragma unroll
    for (int o2 = 0; o2 < 32; ++o2) x2a[o2] += t * w2r[o2];
  }
  #pragma unroll
  for (int o2 = 0; o2 < 32; ++o2) x2a[o2] = fmaxf(x2a[o2], 0.0f);

  float* orow = out + (size_t)b * 7;
  #pragma unroll
  for (int k = 0; k < 7; ++k){
    const float* w3r = W3 + k*32;      // tiny, one-shot: leave as uniform s_load
    float s = b3[k];
    #pragma unroll
    for (int o2 = 0; o2 < 32; ++o2) s += x2a[o2] * w3r[o2];
    orow[k] = s;
  }
}

extern "C" void kernel_launch(void* const* d_in, const int* in_sizes, int n_in,
                              void* d_out, int out_size, void* d_ws, size_t ws_size,
                              hipStream_t stream)
{
  const float* h   = (const float*)d_in[0];
  const float* Wmu = (const float*)d_in[1];
  const float* bmu = (const float*)d_in[2];
  const float* Wk  = (const float*)d_in[3];
  const float* bk  = (const float*)d_in[4];
  const float* W1  = (const float*)d_in[5];
  const float* b1  = (const float*)d_in[6];
  const float* W2  = (const float*)d_in[7];
  const float* b2  = (const float*)d_in[8];
  const float* W3  = (const float*)d_in[9];
  const float* b3  = (const float*)d_in[10];
  const int* seed  = (const int*)d_in[11];

  uint32_t* keys = (uint32_t*)d_ws;
  float* W2T = (float*)((char*)d_ws + 1024);
  float* out = (float*)d_out;

  hipLaunchKernelGGL(prep_kernel, dim3(64), dim3(256), 0, stream, W2, seed, keys, W2T);
  hipLaunchKernelGGL(fused_kernel, dim3(BROWS/512), dim3(512), 0, stream,
                     h, Wmu, bmu, Wk, bk, W1, b1, b2, W3, b3, W2T, keys, out);
}

// Round 9
// 739.391 us; speedup vs baseline: 1.0201x; 1.0109x over previous
//
#include <hip/hip_runtime.h>
#include <hip/hip_bf16.h>
#include <math.h>
#include <stdint.h>

#define NTRY  50
#define BROWS 131072
// output section offsets (floats): out[B*7] | mu[B*32] | kappa[B]
#define OFF_OUT_MU    917504
#define OFF_OUT_KAPPA 5111808

__device__ __forceinline__ uint32_t rotl32(uint32_t x, int r){ return (x << r) | (x >> (32 - r)); }

// Exact JAX threefry2x32 (20 rounds, 5 key injections) — matches jax/_src/prng.py
__device__ __forceinline__ void threefry2x32(uint32_t k0, uint32_t k1,
                                             uint32_t c0, uint32_t c1,
                                             uint32_t& o0, uint32_t& o1){
  const uint32_t k2 = k0 ^ k1 ^ 0x1BD11BDAu;
  uint32_t x0 = c0 + k0;
  uint32_t x1 = c1 + k1;
#define TF_R(r) { x0 += x1; x1 = rotl32(x1, (r)); x1 ^= x0; }
  TF_R(13) TF_R(15) TF_R(26) TF_R(6)
  x0 += k1; x1 += k2 + 1u;
  TF_R(17) TF_R(29) TF_R(16) TF_R(24)
  x0 += k2; x1 += k0 + 2u;
  TF_R(13) TF_R(15) TF_R(26) TF_R(6)
  x0 += k0; x1 += k1 + 3u;
  TF_R(17) TF_R(29) TF_R(16) TF_R(24)
  x0 += k1; x1 += k2 + 4u;
  TF_R(13) TF_R(15) TF_R(26) TF_R(6)
  x0 += k2; x1 += k0 + 5u;
#undef TF_R
  o0 = x0; o1 = x1;
}

// Partitionable random_bits for bit_width=32: bits = out0 ^ out1, counter=(0, idx)
__device__ __forceinline__ uint32_t tf_bits32(uint32_t k0, uint32_t k1, uint32_t idx){
  uint32_t a, b;
  threefry2x32(k0, k1, 0u, idx, a, b);
  return a ^ b;
}

// JAX uniform bit->float: (bits>>9)|0x3f800000 as float, minus 1  -> [0,1)
__device__ __forceinline__ float bits_to_unit(uint32_t bits){
  return __uint_as_float((bits >> 9) | 0x3f800000u) - 1.0f;
}

// f32 log computed via f64 (≈ correctly rounded f32 log)
__device__ __forceinline__ float alogf(float x){
  return (float)log((double)x);
}

// XLA f32 ErfInv polynomial (Giles) — same as xla math.cc ErfInv32
__device__ __forceinline__ float erfinv_f(float x){
  float w = -log1pf(-x * x);
  float p;
  if (w < 5.0f){
    w -= 2.5f;
    p = 2.81022636e-08f;
    p = fmaf(p, w, 3.43273939e-07f);
    p = fmaf(p, w, -3.5233877e-06f);
    p = fmaf(p, w, -4.39150654e-06f);
    p = fmaf(p, w, 0.00021858087f);
    p = fmaf(p, w, -0.00125372503f);
    p = fmaf(p, w, -0.00417768164f);
    p = fmaf(p, w, 0.246640727f);
    p = fmaf(p, w, 1.50140941f);
  } else {
    w = sqrtf(w) - 3.0f;
    p = -0.000200214257f;
    p = fmaf(p, w, 0.000100950558f);
    p = fmaf(p, w, 0.00134934322f);
    p = fmaf(p, w, -0.00367342844f);
    p = fmaf(p, w, 0.00573950773f);
    p = fmaf(p, w, -0.0076224613f);
    p = fmaf(p, w, 0.00943887047f);
    p = fmaf(p, w, 1.00167406f);
    p = fmaf(p, w, 2.83297682f);
  }
  return p * x;
}

// ws layout: keys u32[0..200) = 50*{k1.x,k1.y,k2.x,k2.y}; u32[200..202) = kv
//            float W2Tlo[512][16] at byte 1024 (cols 0..15 of W2^T rows)
//            float W2Thi[512][16] at byte 33792 (cols 16..31)
__global__ void prep_kernel(const float* __restrict__ W2, const int* __restrict__ seedp,
                            uint32_t* __restrict__ keys, float* __restrict__ W2Tlo,
                            float* __restrict__ W2Thi)
{
  const int t = threadIdx.x;
  if (blockIdx.x == 0){
    const uint32_t seed = (uint32_t)seedp[0];
    if (t < NTRY){
      uint32_t f0, f1, a0, a1, b0, b1;
      threefry2x32(0u, seed, 0u, (uint32_t)t, f0, f1);
      threefry2x32(f0, f1, 0u, 0u, a0, a1);
      threefry2x32(f0, f1, 0u, 1u, b0, b1);
      keys[t*4+0] = a0;  // k1
      keys[t*4+1] = a1;
      keys[t*4+2] = b0;  // k2
      keys[t*4+3] = b1;
    } else if (t == NTRY){
      uint32_t f0, f1;
      threefry2x32(0u, seed, 0u, 10000u, f0, f1);
      keys[200] = f0; keys[201] = f1;
    }
  }
  // transpose W2 [32,512] -> split halves; j is output-ish index (coalesced in
  // 64-float runs), reads hit L2 after first touch (64 KB total).
  const int j = blockIdx.x * 256 + t;           // 64*256 = 16384
  const int o1 = j >> 5, o2 = j & 31;
  const float val = W2[o2*512 + o1];
  if (o2 < 16) W2Tlo[o1*16 + o2]      = val;
  else         W2Thi[o1*16 + (o2-16)] = val;
}

// Fused kernel, wave-pair row split: block=512 covers 256 rows; waves 0-3
// (role A) pair with waves 4-7 (role B) on the same rows. Grid 512 -> 2
// blocks/CU -> 16 waves/CU (4/SIMD): doubles TLP over the old 1-row/thread
// structure whose occupancy was structurally capped at 2 waves/SIMD.
// Every accumulation keeps its original order (bit-exact vs measured r8):
//  A: mu-dots 0..15 via LDS; B: dots 16..31 + kappa via s_load  -> LDS exch
//  A: rejection sampling  ||  B: 31 normals (previously sequential) -> exch
//  C: o2-split: A owns x2a[0..15] (W2Tlo via LDS), B owns x2a[16..31]
//     (W2Thi via s_load); both iterate o1=0..511 in order with t redundant;
//     final x2a is a CONCATENATION (no re-associated adds).
// LDS 65 KB: [0,8192) Wmu rows 0..15 -> restaged W2Tlo; [8192,16640) 256x33
// exchange (odd stride -> conflict-free), reused accf -> w/v/vns -> x2a-hi.
__global__ __launch_bounds__(512, 4) void fused_kernel(
    const float* __restrict__ h,
    const float* __restrict__ Wmu, const float* __restrict__ bmu,
    const float* __restrict__ Wk,  const float* __restrict__ bk,
    const float* __restrict__ W1,  const float* __restrict__ b1,
    const float* __restrict__ b2,
    const float* __restrict__ W3,  const float* __restrict__ b3,
    const float* __restrict__ W2Tlo, const float* __restrict__ W2Thi,
    const uint32_t* __restrict__ keys,
    float* __restrict__ out)
{
  __shared__ __align__(16) float lds[16640];   // 65 KiB
  const int tid = threadIdx.x;
  const int rlocal = tid & 255;
  const int role = tid >> 8;                   // wave-uniform
  const int b = blockIdx.x * 256 + rlocal;
  float* exch = &lds[8192 + rlocal * 33];

  const float4* h4 = reinterpret_cast<const float4*>(h + (size_t)b * 512);

  // prefetch h chunk 0 (both roles read the same row; L1/L2 dedups)
  float4 hbuf[8];
  #pragma unroll
  for (int q = 0; q < 8; ++q) hbuf[q] = h4[q];

  // stage Wmu rows 0..15 (32 KiB) into region0
  {
    const float4* Wmu4 = reinterpret_cast<const float4*>(Wmu);
    float4* lds4 = reinterpret_cast<float4*>(lds);
    #pragma unroll
    for (int q = 0; q < 4; ++q) lds4[tid + q*512] = Wmu4[tid + q*512];
  }
  __syncthreads();                             // B1

  // ---------------- phase A: 33 dots of length 512, split by role ----------
  float acc[17];
  #pragma unroll
  for (int i = 0; i < 17; ++i) acc[i] = 0.0f;
  #pragma unroll 1
  for (int ch = 0; ch < 16; ++ch){
    float hv[32];
    #pragma unroll
    for (int q = 0; q < 8; ++q){
      float4 f = hbuf[q];
      hv[q*4+0] = f.x; hv[q*4+1] = f.y; hv[q*4+2] = f.z; hv[q*4+3] = f.w;
    }
    if (ch < 15){
      #pragma unroll
      for (int q = 0; q < 8; ++q) hbuf[q] = h4[(ch+1)*8 + q];
    }
    if (role == 0){
      #pragma unroll
      for (int o = 0; o < 16; ++o){            // LDS broadcast path
        const float4* wr4 = reinterpret_cast<const float4*>(&lds[o*512 + ch*32]);
        float a = acc[o];
        #pragma unroll
        for (int q = 0; q < 8; ++q){
          float4 wq = wr4[q];
          a += hv[q*4+0] * wq.x;
          a += hv[q*4+1] * wq.y;
          a += hv[q*4+2] * wq.z;
          a += hv[q*4+3] * wq.w;
        }
        acc[o] = a;
      }
    } else {
      #pragma unroll
      for (int i = 0; i < 17; ++i){            // scalar path, o compile-time
        const int o = 16 + i;
        const float* wr = (o < 32) ? (Wmu + o*512 + ch*32) : (Wk + ch*32);
        float a = acc[i];
        #pragma unroll
        for (int c = 0; c < 32; ++c) a += hv[c] * wr[c];
        acc[i] = a;
      }
    }
  }

  // exchange acc halves (region1 virgin -> no barrier needed before writes)
  if (role == 0){
    #pragma unroll
    for (int i = 0; i < 16; ++i) exch[i] = acc[i];
  } else {
    #pragma unroll
    for (int i = 0; i < 17; ++i) exch[16 + i] = acc[i];
  }
  __syncthreads();                             // B2: phase-A LDS reads + accf done

  // restage region0 = W2Tlo [512][16] (32 KiB); latency hides under mu+phase B
  {
    const float4* W2Tlo4 = reinterpret_cast<const float4*>(W2Tlo);
    float4 tmp[4];
    #pragma unroll
    for (int q = 0; q < 4; ++q) tmp[q] = W2Tlo4[tid + q*512];
    float4* lds4 = reinterpret_cast<float4*>(lds);
    #pragma unroll
    for (int q = 0; q < 4; ++q) lds4[tid + q*512] = tmp[q];
  }

  float accf[33];
  #pragma unroll
  for (int o = 0; o < 33; ++o) accf[o] = exch[o];

  // mu/kappa redundantly on both roles — bit-exact, order preserved
  float mu[32]; float nsq = 0.0f;
  #pragma unroll
  for (int o = 0; o < 32; ++o){ float m = accf[o] + bmu[o]; mu[o] = m; nsq += m*m; }
  const float invn = 1.0f / fmaxf(sqrtf(nsq), 1e-12f);
  #pragma unroll
  for (int o = 0; o < 32; ++o) mu[o] *= invn;

  const float xk = accf[32] + bk[0];
  const float kappa = (float)log1p(exp((double)xk)) + 1.0f;   // softplus(x)+1

  if (role == 0){
    float4* mo = reinterpret_cast<float4*>(out + OFF_OUT_MU + (size_t)b * 32);
    #pragma unroll
    for (int q = 0; q < 8; ++q){
      float4 f; f.x = mu[q*4+0]; f.y = mu[q*4+1]; f.z = mu[q*4+2]; f.w = mu[q*4+3];
      mo[q] = f;
    }
    out[OFF_OUT_KAPPA + b] = kappa;
  }
  __syncthreads();                             // B3: accf reads done, W2Tlo staged

  // ---------------- phase B: rejection (A)  ||  normals (B) ----------------
  const uint32_t ub = (uint32_t)b;
  if (role == 0){
    float w = 0.0f; bool done = false;
    #pragma unroll 2
    for (int i = 0; i < NTRY; ++i){
      #pragma clang fp contract(off)
      const uint32_t K0 = keys[i*4+0], K1 = keys[i*4+1];
      const uint32_t K2 = keys[i*4+2], K3 = keys[i*4+3];
      const float u1 = bits_to_unit(tf_bits32(K0, K1, ub));   // w_cand
      const float u2 = bits_to_unit(tf_bits32(K2, K3, ub));   // log_r
      const float wc   = 2.0f * u1 - 1.0f;
      const float ww   = wc * wc;
      const float omw2 = fmaxf(1.0f - ww, 1e-38f);
      const float lg   = alogf(omw2);
      const float lp   = kappa * wc + 14.5f * lg;   // 0.5*(alpha-2)=14.5
      const float lr   = alogf(u2 + 1e-38f);
      const bool  cnd  = (lr + kappa <= lp) && !done;
      if (cnd){ w = wc; done = true; }
      if (__all(done)) break;                   // exact: skipped iters change nothing
    }
    w = fminf(fmaxf(w, -1.0f), 1.0f);
    exch[32] = w;
  } else {
    const uint32_t kv0 = keys[200], kv1 = keys[201];
    float vns = 0.0f;
    const uint32_t e0 = ub * 31u;
    #pragma unroll
    for (int j = 0; j < 31; ++j){
      const float uf01 = bits_to_unit(tf_bits32(kv0, kv1, e0 + (uint32_t)j));
      const float u = fmaxf(uf01 * 2.0f + (-0.99999994f), -0.99999994f);
      const float g = 1.4142135623730951f * erfinv_f(u);
      exch[j] = g; vns += g * g;
    }
    exch[31] = vns;
  }
  __syncthreads();                             // B4: w + v + vns ready

  const float w = exch[32];
  float v[31];
  #pragma unroll
  for (int j = 0; j < 31; ++j) v[j] = exch[j];
  const float vns = exch[31];

  // z built redundantly on both roles — bit-exact
  const float invvn = 1.0f / fmaxf(sqrtf(vns), 1e-12f);
  const float st = sqrtf(fmaxf(1.0f - w * w, 1e-38f));
  float zt[32];
  #pragma unroll
  for (int j = 0; j < 31; ++j) zt[j] = st * (v[j] * invvn);
  zt[31] = w;

  float ue[32]; float uns = 0.0f;
  #pragma unroll
  for (int o = 0; o < 32; ++o){
    float e = ((o == 31) ? 1.0f : 0.0f) - mu[o];
    ue[o] = e; uns += e * e;
  }
  const float invun = 1.0f / fmaxf(sqrtf(uns), 1e-12f);
  float dot = 0.0f;
  #pragma unroll
  for (int o = 0; o < 32; ++o){ ue[o] *= invun; dot += zt[o] * ue[o]; }
  float z[32];
  #pragma unroll
  for (int o = 0; o < 32; ++o) z[o] = zt[o] - 2.0f * dot * ue[o];

  // ---------------- phase C: MLP, o2-split across the pair -----------------
  float x2a[16];
  #pragma unroll
  for (int k = 0; k < 16; ++k) x2a[k] = b2[role*16 + k];
  if (role == 0){
    #pragma unroll 2
    for (int o1 = 0; o1 < 512; ++o1){
      const float* w1r = W1 + o1*32;           // uniform s_load (shared stream)
      float t = b1[o1];
      #pragma unroll
      for (int j = 0; j < 32; ++j) t += z[j] * w1r[j];
      t = fmaxf(t, 0.0f);
      const float4* w2r4 = reinterpret_cast<const float4*>(&lds[o1*16]);  // LDS broadcast
      #pragma unroll
      for (int q = 0; q < 4; ++q){
        float4 wq = w2r4[q];
        x2a[q*4+0] += t * wq.x;
        x2a[q*4+1] += t * wq.y;
        x2a[q*4+2] += t * wq.z;
        x2a[q*4+3] += t * wq.w;
      }
    }
  } else {
    #pragma unroll 2
    for (int o1 = 0; o1 < 512; ++o1){
      const float* w1r = W1 + o1*32;
      float t = b1[o1];
      #pragma unroll
      for (int j = 0; j < 32; ++j) t += z[j] * w1r[j];
      t = fmaxf(t, 0.0f);
      const float* w2r = W2Thi + o1*16;        // uniform s_load
      #pragma unroll
      for (int k = 0; k < 16; ++k) x2a[k] += t * w2r[k];
    }
  }
  __syncthreads();                             // B5: z-piece reads long done
  if (role == 1){
    #pragma unroll
    for (int k = 0; k < 16; ++k) exch[k] = x2a[k];
  }
  __syncthreads();                             // B6: x2a-hi ready
  if (role == 0){
    float xf[32];
    #pragma unroll
    for (int k = 0; k < 16; ++k) xf[k] = fmaxf(x2a[k], 0.0f);
    #pragma unroll
    for (int k = 0; k < 16; ++k) xf[16 + k] = fmaxf(exch[k], 0.0f);
    float* orow = out + (size_t)b * 7;
    #pragma unroll
    for (int kk = 0; kk < 7; ++kk){
      const float* w3r = W3 + kk*32;
      float s = b3[kk];
      #pragma unroll
      for (int o2 = 0; o2 < 32; ++o2) s += xf[o2] * w3r[o2];
      orow[kk] = s;
    }
  }
}

extern "C" void kernel_launch(void* const* d_in, const int* in_sizes, int n_in,
                              void* d_out, int out_size, void* d_ws, size_t ws_size,
                              hipStream_t stream)
{
  const float* h   = (const float*)d_in[0];
  const float* Wmu = (const float*)d_in[1];
  const float* bmu = (const float*)d_in[2];
  const float* Wk  = (const float*)d_in[3];
  const float* bk  = (const float*)d_in[4];
  const float* W1  = (const float*)d_in[5];
  const float* b1  = (const float*)d_in[6];
  const float* W2  = (const float*)d_in[7];
  const float* b2  = (const float*)d_in[8];
  const float* W3  = (const float*)d_in[9];
  const float* b3  = (const float*)d_in[10];
  const int* seed  = (const int*)d_in[11];

  uint32_t* keys = (uint32_t*)d_ws;
  float* W2Tlo = (float*)((char*)d_ws + 1024);
  float* W2Thi = (float*)((char*)d_ws + 1024 + 32768);
  float* out = (float*)d_out;

  hipLaunchKernelGGL(prep_kernel, dim3(64), dim3(256), 0, stream, W2, seed, keys, W2Tlo, W2Thi);
  hipLaunchKernelGGL(fused_kernel, dim3(BROWS/256), dim3(512), 0, stream,
                     h, Wmu, bmu, Wk, bk, W1, b1, b2, W3, b3, W2Tlo, W2Thi, keys, out);
}